// Round 1
// baseline (233.243 us; speedup 1.0000x reference)
//
#include <hip/hip_runtime.h>
#include <math.h>

// UpPolyAct: out = c0 + c1*x + 0.25*c2*( z_ee + V + W )
//   R = X M^T, L = M X, OO = L M^T
//   z_eo=(R+corr)^2, z_oe=(L+corr)^2, z_oo=OO^2, z_ee=(E X E)^2
//   U = z_oe + z_oo M,  V = M^T U,  W = z_eo M
// MFMA plan (32x32x16 bf16, 1 tile/wave, T-domain through U):
//   Rt = M X^T        A=tab(gr,rb)  B=Xr rows
//   Lt = X^T M^T      A=Xc rows     B=tab(gr,cb)
//   OOt = M Lt        A=tab(gr,rb)  B=Lr rows      (Lr = L row-major, T-write)
//   Ut = zoeT + M^T zooT   A=tab(g,rb)  B=Zoo rows (acc init = z_oeT regs)
//   W  = z_eo M       A=Zeo rows    B=tab(g,cb)    (untransposed)
//   V  = M^T U        A=tab(g,rb)   B=UtR rows     (untransposed)
//
// R1 changes vs baseline:
//  - persistent blocks: grid=1024, 4 channels/block, g64+ftab built ONCE per
//    block (table build kept bit-identical to baseline)
//  - tvec/uvec/sRv/Luv/sigv parallelized across all 256 threads
//    (vectorized short8 loads + __shfl_xor pair reduce; wave-uniform branches)

typedef short short8 __attribute__((ext_vector_type(8)));
typedef float f32x16 __attribute__((ext_vector_type(16)));

#define LSH 68  // bf16 LDS row stride (68 shorts = 136 B, rows 8B-aligned)

__device__ __forceinline__ short f2bf(float f) {
  unsigned u = __float_as_uint(f);
  u += 0x7FFFu + ((u >> 16) & 1u);
  return (short)(u >> 16);
}
__device__ __forceinline__ float bf2f(short s) {
  return __uint_as_float(((unsigned)(unsigned short)s) << 16);
}
__device__ __forceinline__ short8 ldrow(const short* p) {
  union { unsigned u[4]; short8 s; } v;
  const uint2 lo = *(const uint2*)p;
  const uint2 hi = *(const uint2*)(p + 4);
  v.u[0] = lo.x; v.u[1] = lo.y; v.u[2] = hi.x; v.u[3] = hi.y;
  return v.s;
}

__global__ __launch_bounds__(256, 3) void uppolyact_kernel(
    const float* __restrict__ x, const float* __restrict__ coef,
    float* __restrict__ out, int nch) {
  __shared__ __align__(16) short Xr[64 * LSH];    // X row-major bf16
  __shared__ __align__(16) short XcZ[64 * LSH];   // X^T row-major, then z_eo row-major
  __shared__ __align__(16) short LrU[64 * LSH];   // L row-major, then U^T row-major
  __shared__ __align__(16) short Zoo[64 * LSH];   // z_oo row-major
  __shared__ __align__(16) short ftab[16 * 64 * 8];  // M fragments, slot=(t*2+blk)*4+kk
  __shared__ float g64[64];
  __shared__ float tvec[64], uvec[64], sRv[64], Luv[64];
  __shared__ float sigv;

  const int tid = threadIdx.x;
  const int lane = tid & 63;
  const int w = tid >> 6;
  const int q = lane >> 5;
  const int l31 = lane & 31;
  const int rb = w >> 1, cb = w & 1;

  // ---- once per block: g table (bit-identical to baseline) ----
  if (tid < 64) {
    const int d = 2 * tid + 1;
    float s = 1.0f;
    for (int k = 1; k <= 32; ++k) {
      const int qq = (k * d) & 127;
      s += 2.0f * cosf((float)M_PI * (1.0f / 64.0f) * (float)qq);
    }
    g64[tid] = s * (1.0f / 64.0f);
  }
  __syncthreads();

  // ---- once per block: M fragment table ----
#pragma unroll
  for (int e = 0; e < 4; ++e) {
    const int entry = tid + 256 * e;  // 0..1023
    const int s_ = entry >> 6, ln = entry & 63;
    const int t_ = s_ >> 3, blk = (s_ >> 2) & 1, kk = s_ & 3;
    const int basei = kk * 16 + (ln >> 5) * 8 - (ln & 31) - 32 * blk;
    short* dst = &ftab[(s_ * 64 + ln) * 8];
#pragma unroll
    for (int j = 0; j < 8; ++j) {
      const int i0 = basei + j;
      const int idx = t_ ? ((-i0) & 63) : (i0 & 63);
      dst[j] = f2bf(g64[idx]);
    }
  }

  const float c0 = coef[0], c1 = coef[1];
  const float c2q = 0.25f * coef[2];

  for (int ch = blockIdx.x; ch < nch; ch += gridDim.x) {
    const size_t base = (size_t)ch * 4096;
    const float* xb = x + base;
    float* ob = out + base;

    __syncthreads();  // B0: ftab ready / prior channel fully consumed

    // ---- P0: load X -> Xr + Xc (bf16) ----
    {
      const float4* xv = (const float4*)xb;
#pragma unroll
      for (int e = 0; e < 4; ++e) {
        const int k4 = tid + 256 * e;  // 0..1023 float4s
        const float4 v = xv[k4];
        const int r = k4 >> 4, c = (k4 & 15) << 2;
        const short b0 = f2bf(v.x), b1 = f2bf(v.y), b2 = f2bf(v.z), b3 = f2bf(v.w);
        short* pr = &Xr[r * LSH + c];
        pr[0] = b0; pr[1] = b1; pr[2] = b2; pr[3] = b3;
        XcZ[(c + 0) * LSH + r] = b0;
        XcZ[(c + 1) * LSH + r] = b1;
        XcZ[(c + 2) * LSH + r] = b2;
        XcZ[(c + 3) * LSH + r] = b3;
      }
    }
    __syncthreads();  // B1

    // ---- M1: tvec/uvec with all 256 threads (vectorized) ----
    // tvec[j] = sum_i sign_i X[i][j]   (rows of XcZ, contiguous)
    // uvec[i] = sum_j X[i][j] sign_j   (rows of Xr, contiguous)
    {
      const int o = tid >> 1, h = tid & 1;  // o: output 0..127, h: half
      const short* src = (o < 64) ? &XcZ[o * LSH + 32 * h]
                                  : &Xr[(o - 64) * LSH + 32 * h];
      float acc = 0.0f;
#pragma unroll
      for (int p = 0; p < 4; ++p) {
        const short8 v = ldrow(src + 8 * p);
#pragma unroll
        for (int j = 0; j < 8; ++j) {
          const float f = bf2f(v[j]);
          acc += (j & 1) ? -f : f;  // element index 32h+8p+j, parity = j&1
        }
      }
      acc += __shfl_xor(acc, 1);
      if (h == 0) {
        if (o < 64) tvec[o] = acc; else uvec[o - 64] = acc;
      }
    }

    // ---- MFMA Rt, Lt (independent of M1 results) ----
    f32x16 Rt, Lt;
#pragma unroll
    for (int r = 0; r < 16; ++r) { Rt[r] = 0.0f; Lt[r] = 0.0f; }
#pragma unroll
    for (int kk = 0; kk < 4; ++kk) {
      const short8 aR = *(const short8*)&ftab[(((2 + rb) * 4 + kk) * 64 + lane) * 8];  // (gr,rb)
      const short8 bR = ldrow(&Xr[(cb * 32 + l31) * LSH + kk * 16 + q * 8]);
      Rt = __builtin_amdgcn_mfma_f32_32x32x16_bf16(aR, bR, Rt, 0, 0, 0);
      const short8 aL = ldrow(&XcZ[(rb * 32 + l31) * LSH + kk * 16 + q * 8]);
      const short8 bL = *(const short8*)&ftab[(((2 + cb) * 4 + kk) * 64 + lane) * 8];  // (gr,cb)
      Lt = __builtin_amdgcn_mfma_f32_32x32x16_bf16(aL, bL, Lt, 0, 0, 0);
    }
    __syncthreads();  // B2: tvec/uvec visible; Xr/XcZ reads of this phase done

    // ---- M2: sRv/Luv with all 256 threads; sigv on wave 0 ----
    // sRv[j] = sum_m tvec[m]*g64[(j-m)&63] ; Luv[i] = sum_m g64[(i-m)&63]*uvec[m]
    {
      const int o = tid >> 1, h = tid & 1;
      const int o63 = o & 63;
      const float* vsrc = (o < 64) ? tvec : uvec;  // wave-uniform select
      float acc = 0.0f;
#pragma unroll
      for (int p = 0; p < 32; ++p) {
        const int m = 32 * h + p;
        acc += vsrc[m] * g64[(o63 - m) & 63];
      }
      acc += __shfl_xor(acc, 1);
      if (h == 0) {
        if (o < 64) sRv[o] = acc; else Luv[o - 64] = acc;
      }
    }
    if (w == 0) {  // sigv = s^T X s = sum_j sign_j * tvec[j]
      float sv = (lane & 1) ? -tvec[lane] : tvec[lane];
#pragma unroll
      for (int d_ = 1; d_ < 64; d_ <<= 1) sv += __shfl_xor(sv, d_);
      if (lane == 0) sigv = sv;
    }
    __syncthreads();  // B3

    // ---- P2: z_eoT -> XcZ (T-write), Lt -> LrU (T-write), z_oeT regs ----
    float zoe[16];
#pragma unroll
    for (int r = 0; r < 16; ++r) {
      const int jrow = rb * 32 + (r & 3) + 4 * q + 8 * (r >> 2);
      const int icol = cb * 32 + l31;
      const float sgi = (icol & 1) ? -1.0f : 1.0f;
      const float sgj = (jrow & 1) ? -1.0f : 1.0f;
      const float veo = Rt[r] + sgi * sRv[jrow] * (1.0f / 64.0f);
      XcZ[icol * LSH + jrow] = f2bf(veo * veo);   // z_eo[i][j]
      LrU[icol * LSH + jrow] = f2bf(Lt[r]);       // L[i][j]
      const float voe = Lt[r] + Luv[icol] * sgj * (1.0f / 64.0f);
      zoe[r] = voe * voe;                         // z_oeT[j][i] (C-layout)
    }
    __syncthreads();  // B4

    // ---- P3: OOt = M*Lt ; z_oo -> Zoo (T-write) ----
    f32x16 OOt;
#pragma unroll
    for (int r = 0; r < 16; ++r) OOt[r] = 0.0f;
#pragma unroll
    for (int kk = 0; kk < 4; ++kk) {
      const short8 a = *(const short8*)&ftab[(((2 + rb) * 4 + kk) * 64 + lane) * 8];  // (gr,rb)
      const short8 b = ldrow(&LrU[(cb * 32 + l31) * LSH + kk * 16 + q * 8]);
      OOt = __builtin_amdgcn_mfma_f32_32x32x16_bf16(a, b, OOt, 0, 0, 0);
    }
#pragma unroll
    for (int r = 0; r < 16; ++r) {
      const int jrow = rb * 32 + (r & 3) + 4 * q + 8 * (r >> 2);
      const int icol = cb * 32 + l31;
      Zoo[icol * LSH + jrow] = f2bf(OOt[r] * OOt[r]);  // z_oo[i][j]
    }
    __syncthreads();  // B5

    // ---- P4: Ut = z_oeT + M^T z_ooT ; W = z_eo*M ; Ut -> LrU direct ----
    f32x16 Ut, Wv;
#pragma unroll
    for (int r = 0; r < 16; ++r) { Ut[r] = zoe[r]; Wv[r] = 0.0f; }
#pragma unroll
    for (int kk = 0; kk < 4; ++kk) {
      const short8 aU = *(const short8*)&ftab[(((0 + rb) * 4 + kk) * 64 + lane) * 8];  // (g,rb)
      const short8 bU = ldrow(&Zoo[(cb * 32 + l31) * LSH + kk * 16 + q * 8]);
      Ut = __builtin_amdgcn_mfma_f32_32x32x16_bf16(aU, bU, Ut, 0, 0, 0);
      const short8 aW = ldrow(&XcZ[(rb * 32 + l31) * LSH + kk * 16 + q * 8]);  // z_eo rows
      const short8 bW = *(const short8*)&ftab[(((0 + cb) * 4 + kk) * 64 + lane) * 8];  // (g,cb)
      Wv = __builtin_amdgcn_mfma_f32_32x32x16_bf16(aW, bW, Wv, 0, 0, 0);
    }
#pragma unroll
    for (int r = 0; r < 16; ++r) {
      const int jrow = rb * 32 + (r & 3) + 4 * q + 8 * (r >> 2);
      const int icol = cb * 32 + l31;
      LrU[jrow * LSH + icol] = f2bf(Ut[r]);  // U^T row-major (rows=j)
    }
    __syncthreads();  // B6

    // ---- P5: V = M^T U ; epilogue ----
    f32x16 Vv;
#pragma unroll
    for (int r = 0; r < 16; ++r) Vv[r] = 0.0f;
#pragma unroll
    for (int kk = 0; kk < 4; ++kk) {
      const short8 a = *(const short8*)&ftab[(((0 + rb) * 4 + kk) * 64 + lane) * 8];  // (g,rb)
      const short8 b = ldrow(&LrU[(cb * 32 + l31) * LSH + kk * 16 + q * 8]);
      Vv = __builtin_amdgcn_mfma_f32_32x32x16_bf16(a, b, Vv, 0, 0, 0);
    }

#pragma unroll
    for (int r = 0; r < 16; ++r) {
      const int irow = rb * 32 + (r & 3) + 4 * q + 8 * (r >> 2);
      const int jcol = cb * 32 + l31;
      const float sgi = (irow & 1) ? -1.0f : 1.0f;
      const float sgj = (jcol & 1) ? -1.0f : 1.0f;
      const float xv_ = bf2f(Xr[irow * LSH + jcol]);
      const float vee = xv_ + (sgi * tvec[jcol] + uvec[irow] * sgj) * (1.0f / 64.0f) +
                        sgi * sgj * sigv * (1.0f / 4096.0f);
      const float zee = vee * vee;
      const float xg = xb[irow * 64 + jcol];
      ob[irow * 64 + jcol] = c0 + c1 * xg + c2q * (zee + Vv[r] + Wv[r]);
    }
  }
}

extern "C" void kernel_launch(void* const* d_in, const int* in_sizes, int n_in,
                              void* d_out, int out_size, void* d_ws,
                              size_t ws_size, hipStream_t stream) {
  const float* x = (const float*)d_in[0];
  const float* coef = (const float*)d_in[1];
  float* out = (float*)d_out;
  const int channels = out_size / 4096;  // 32*128 channels of 64x64
  int grid = 1024;  // 4 channels/block at full residency (3 blocks/CU x 256 CU)
  if (grid > channels) grid = channels;
  uppolyact_kernel<<<dim3(grid), dim3(256), 0, stream>>>(x, coef, out, channels);
}